// Round 11
// baseline (303.401 us; speedup 1.0000x reference)
//
#include <hip/hip_runtime.h>
#include <stdint.h>

#define BB   512
#define NN   512
#define MROWS (BB*NN)      // 262144
#define RT   (MROWS/64)    // 4096 row tiles of 64
#define EPSV 1e-5f

typedef unsigned short u16;
typedef __attribute__((ext_vector_type(8))) short bf16x8;
typedef __attribute__((ext_vector_type(4))) float f32x4;

// ---------- helpers ----------
__device__ __forceinline__ float read_mask(const void* mp, int r, int mode) {
  if (mode == 0) return ((const unsigned char*)mp)[r] ? 1.f : 0.f;
  if (mode == 1) return ((const unsigned int*)mp)[r] ? 1.f : 0.f;
  return ((const unsigned long long*)mp)[r] ? 1.f : 0.f;
}

__device__ __forceinline__ u16 f2bf(float f) {
  union { float f; unsigned int u; } v; v.f = f;
  unsigned int u = v.u;
  return (u16)((u + 0x7FFFu + ((u >> 16) & 1u)) >> 16);
}

__device__ __forceinline__ float bf2f(u16 b) {
  union { unsigned int u; float f; } t;
  t.u = ((unsigned int)b) << 16;
  return t.f;
}

// packed f32x2 -> bf16x2 (RTNE, identical to f2bf), 1 VALU instr for 2 values
__device__ __forceinline__ unsigned int cvt_pk_bf16(float lo, float hi) {
  unsigned int r;
  asm("v_cvt_pk_bf16_f32 %0, %1, %2" : "=v"(r) : "v"(lo), "v"(hi));
  return r;
}

// ---------- merged weight prep + mask-mode detect + accumulator zeroing ----------
// blocks 0..255: W2t/W4t; 256..384: W23t + c23; 385: detect + zero midS/midQ/ctr.
__global__ __launch_bounds__(256) void k_prep(
    const float* __restrict__ W2, const float* __restrict__ W3, const float* __restrict__ W4,
    const float* __restrict__ b2, const unsigned char* __restrict__ mu,
    u16* __restrict__ w2t, u16* __restrict__ w4t,
    u16* __restrict__ w23t, float* __restrict__ c23, int* __restrict__ mode,
    float* __restrict__ midS, float* __restrict__ midQ, int* __restrict__ ctr) {
  __shared__ float row[256];
  __shared__ int c1s, c4s;
  const int blk = blockIdx.x;
  if (blk < 256) {
    const int idx = blk*256 + threadIdx.x;  // < 65536
    if (idx < 32768) {                 // W2t [256 n][128 k]
      const int n = idx >> 7, k = idx & 127;
      w2t[idx] = f2bf(W2[(size_t)k*256 + n]);
    } else {                           // W4t [128 n][256 k]
      const int j = idx - 32768;
      const int n = j >> 8, k = j & 255;
      w4t[j] = f2bf(W4[(size_t)k*128 + n]);
    }
  } else if (blk < 385) {
    const int n = threadIdx.x;
    const int k = blk - 256;   // 0..128; k==128 computes c23
    if (k < 128) {
      row[n] = W2[(size_t)k*256 + n];
      __syncthreads();
      float a0 = 0.f, a1 = 0.f, a2v = 0.f, a3 = 0.f;
      for (int j = 0; j < 256; j += 4) {
        a0 = fmaf(row[j  ], W3[(size_t)(j    )*256 + n], a0);
        a1 = fmaf(row[j+1], W3[(size_t)(j + 1)*256 + n], a1);
        a2v= fmaf(row[j+2], W3[(size_t)(j + 2)*256 + n], a2v);
        a3 = fmaf(row[j+3], W3[(size_t)(j + 3)*256 + n], a3);
      }
      w23t[(size_t)n*128 + k] = f2bf(((a0 + a1) + (a2v + a3)));
    } else {
      float a0 = 0.f, a1 = 0.f, a2v = 0.f, a3 = 0.f;
      for (int j = 0; j < 256; j += 4) {
        a0 = fmaf(b2[j  ], W3[(size_t)(j    )*256 + n], a0);
        a1 = fmaf(b2[j+1], W3[(size_t)(j + 1)*256 + n], a1);
        a2v= fmaf(b2[j+2], W3[(size_t)(j + 2)*256 + n], a2v);
        a3 = fmaf(b2[j+3], W3[(size_t)(j + 3)*256 + n], a3);
      }
      c23[n] = ((a0 + a1) + (a2v + a3));
    }
  } else {
    // zero the k_pool2 accumulators (must happen EVERY launch: graph replay)
    midS[threadIdx.x] = 0.f;
    midQ[threadIdx.x] = 0.f;
    if (threadIdx.x == 0) *ctr = 0;
    // detect mask element layout
    if (threadIdx.x == 0) { c1s = 0; c4s = 0; }
    __syncthreads();
    for (int i = threadIdx.x; i < 4096; i += 256) {
      const unsigned char b = mu[i];
      if (b) {
        if ((i & 3) == 1) atomicAdd(&c1s, 1);
        if ((i & 7) == 4) atomicAdd(&c4s, 1);
      }
    }
    __syncthreads();
    if (threadIdx.x == 0) *mode = c1s ? 0 : (c4s ? 1 : 2);
  }
}

// ---------- kernel 1: CLOSED-FORM BN1 stats via x moments ----------
// part[blk][32]: 0..5 Sx, 6..26 Sxx (packed upper tri), 27 unused, 28..31 per-batch counts.
__global__ __launch_bounds__(256) void k_stats1(
    const float* __restrict__ x, const void* __restrict__ mask,
    const int* __restrict__ modep,
    float* __restrict__ part, float* __restrict__ cntbf) {
  const int mode = *modep;
  const int tid = threadIdx.x;
  const int blk = blockIdx.x;          // handles batches 4*blk .. 4*blk+3
  float sx[6] = {0,0,0,0,0,0};
  float sxx[21] = {0};
  float cntq[4] = {0,0,0,0};
#pragma unroll
  for (int it = 0; it < 8; ++it) {
    const int r = blk*2048 + it*256 + tid;
    const float mv = read_mask(mask, r, mode);
    const float* xr = x + (size_t)r*6;
    const float2 p0 = *(const float2*)(xr);
    const float2 p1 = *(const float2*)(xr + 2);
    const float2 p2 = *(const float2*)(xr + 4);
    float v[6] = {p0.x, p0.y, p1.x, p1.y, p2.x, p2.y};
    cntq[it >> 1] += mv;
    int idx = 0;
#pragma unroll
    for (int j = 0; j < 6; ++j) {
      sx[j] = fmaf(mv, v[j], sx[j]);
      const float mj = mv * v[j];
#pragma unroll
      for (int k = j; k < 6; ++k) { sxx[idx] = fmaf(mj, v[k], sxx[idx]); ++idx; }
    }
  }
  float vals[32];
#pragma unroll
  for (int j = 0; j < 6; ++j) vals[j] = sx[j];
#pragma unroll
  for (int j = 0; j < 21; ++j) vals[6 + j] = sxx[j];
  vals[27] = 0.f;
#pragma unroll
  for (int q = 0; q < 4; ++q) vals[28 + q] = cntq[q];
#pragma unroll
  for (int j = 0; j < 32; ++j) {
#pragma unroll
    for (int m = 1; m <= 32; m <<= 1)
      vals[j] += __shfl_xor(vals[j], m, 64);
  }
  __shared__ float red[4][32];
  const int wave = tid >> 6, lane = tid & 63;
  if (lane == 0) {
#pragma unroll
    for (int j = 0; j < 32; ++j) red[wave][j] = vals[j];
  }
  __syncthreads();
  if (tid < 32) {
    const float tot = red[0][tid] + red[1][tid] + red[2][tid] + red[3][tid];
    part[(size_t)blk*32 + tid] = tot;
    if (tid >= 28) cntbf[blk*4 + (tid - 28)] = tot;
  }
}

// ---------- kernel 2: reduce moments + closed-form BN1 -> folded W1p, c1p ----------
__global__ __launch_bounds__(128) void k_fin1(
    const float* __restrict__ part,
    const float* __restrict__ W1, const float* __restrict__ b1,
    const float* __restrict__ g1, const float* __restrict__ be1,
    float* __restrict__ w1p, float* __restrict__ c1p, float* __restrict__ cntf) {
  __shared__ float tot[32];
  const int t = threadIdx.x;
  if (t < 32) {
    float a0 = 0.f, a1 = 0.f, a2v = 0.f, a3 = 0.f;
    for (int i = 0; i < 128; i += 4) {
      a0 += part[(size_t)(i    )*32 + t];
      a1 += part[(size_t)(i + 1)*32 + t];
      a2v+= part[(size_t)(i + 2)*32 + t];
      a3 += part[(size_t)(i + 3)*32 + t];
    }
    tot[t] = (a0 + a1) + (a2v + a3);
  }
  __syncthreads();
  float cnt = tot[28] + tot[29] + tot[30] + tot[31];
  if (cnt < 1.f) cnt = 1.f;
  if (t == 0) *cntf = cnt;
  const int c = t;
  float w[6];
#pragma unroll
  for (int k = 0; k < 6; ++k) w[k] = W1[k*128 + c];
  float s1 = 0.f;
#pragma unroll
  for (int k = 0; k < 6; ++k) s1 = fmaf(w[k], tot[k], s1);
  s1 /= cnt;
  float q = 0.f;
  {
    int idx = 6;
#pragma unroll
    for (int j = 0; j < 6; ++j) {
      q = fmaf(w[j]*w[j], tot[idx], q); ++idx;
#pragma unroll
      for (int k = j + 1; k < 6; ++k) { q = fmaf(2.f*w[j]*w[k], tot[idx], q); ++idx; }
    }
  }
  float var = q / cnt - s1*s1; if (var < 0.f) var = 0.f;
  const float mean = b1[c] + s1;
  const float a = g1[c] * rsqrtf(var + EPSV);
  c1p[c] = fmaf(b1[c], a, be1[c] - mean*a);
#pragma unroll
  for (int k = 0; k < 6; ++k) w1p[k*128 + c] = W1[k*128 + c] * a;
}

// ---------- MEGA kernel (proven 101 us): GEMM1+BN1+ReLU -> hA;
//   GEMM2 (K=128) -> pool col-max only; GEMM23 (K=128) -> acc3 bf16 store + BN2 stats ----------
__global__ __launch_bounds__(256, 4) void k_mega(
    const float* __restrict__ x, const void* __restrict__ mask, const int* __restrict__ modep,
    const float* __restrict__ w1p, const float* __restrict__ c1p,
    const u16* __restrict__ W2t, const float* __restrict__ b2,
    const u16* __restrict__ W23t, const float* __restrict__ c23,
    u16* __restrict__ acc3buf, float* __restrict__ poolpart,
    float* __restrict__ s2sum, float* __restrict__ s2sq) {
  __shared__ u16 buf[64*264];    // hA (pitch 136), later acc3 staging (pitch 264)
  __shared__ float xs[384];
  __shared__ float mk[64];
  const int mode = *modep;
  const int tid = threadIdx.x;
  const int rt = blockIdx.x;
  const int row0 = rt*64;
  const int b = rt >> 3, seg = rt & 7;
  for (int i = tid; i < 384; i += 256) xs[i] = x[(size_t)row0*6 + i];
  if (tid < 64) mk[tid] = read_mask(mask, row0 + tid, mode);
  __syncthreads();
  // phase 1: h1n = relu(x@W1' + c1') bf16 into hA (pitch 136 inside buf).
  {
    const int c0 = (tid & 31) * 4;
    const int r0 = (tid >> 5) * 8;
    float4 wv[6];
#pragma unroll
    for (int k = 0; k < 6; ++k) wv[k] = *(const float4*)(w1p + k*128 + c0);
    const float4 cc = *(const float4*)(c1p + c0);
#pragma unroll
    for (int r = 0; r < 8; ++r) {
      const int row = r0 + r;
      float xv[6];
#pragma unroll
      for (int k = 0; k < 6; ++k) xv[k] = xs[row*6 + k];
      float v0 = cc.x, v1 = cc.y, v2 = cc.z, v3 = cc.w;
#pragma unroll
      for (int k = 0; k < 6; ++k) {
        v0 = fmaf(xv[k], wv[k].x, v0);
        v1 = fmaf(xv[k], wv[k].y, v1);
        v2 = fmaf(xv[k], wv[k].z, v2);
        v3 = fmaf(xv[k], wv[k].w, v3);
      }
      uint2 z;
      z.x = cvt_pk_bf16(fmaxf(v0, 0.f), fmaxf(v1, 0.f));
      z.y = cvt_pk_bf16(fmaxf(v2, 0.f), fmaxf(v3, 0.f));
      *(uint2*)(buf + row*136 + c0) = z;
    }
  }
  __syncthreads();
  const int wave = tid >> 6, lane = tid & 63;
  const int lr = lane & 15, lq = lane >> 4;
  // phase 2: GEMM2 (64 x 256, K=128) -> pool col-max only (no store)
  {
    f32x4 acc[4][4];
#pragma unroll
    for (int r = 0; r < 4; ++r)
#pragma unroll
      for (int c = 0; c < 4; ++c) acc[r][c] = (f32x4){0.f,0.f,0.f,0.f};
#pragma unroll
    for (int kc = 0; kc < 128; kc += 32) {
      bf16x8 afr[4];
#pragma unroll
      for (int r = 0; r < 4; ++r)
        afr[r] = *(const bf16x8*)(buf + (r*16 + lr)*136 + kc + lq*8);
#pragma unroll
      for (int c = 0; c < 4; ++c) {
        const bf16x8 bfr = *(const bf16x8*)(W2t + (size_t)(wave*64 + c*16 + lr)*128 + kc + lq*8);
#pragma unroll
        for (int r = 0; r < 4; ++r)
          acc[r][c] = __builtin_amdgcn_mfma_f32_16x16x32_bf16(afr[r], bfr, acc[r][c], 0, 0, 0);
      }
    }
#pragma unroll
    for (int c = 0; c < 4; ++c) {
      const int col = wave*64 + c*16 + lr;
      const float bb = b2[col];
      float cm = -1e38f;
#pragma unroll
      for (int r = 0; r < 4; ++r) {
        const int base = r*16 + lq*4;
#pragma unroll
        for (int i = 0; i < 4; ++i)
          cm = fmaxf(cm, (acc[r][c][i] + bb) * mk[base + i]);
      }
      cm = fmaxf(cm, __shfl_xor(cm, 16, 64));
      cm = fmaxf(cm, __shfl_xor(cm, 32, 64));
      if (lq == 0) poolpart[((size_t)(b*8 + seg))*256 + col] = cm;
    }
  }
  // phase 23: acc3 = relu1 @ W23 (64 x 256, K=128) from hA -- no barrier needed
  f32x4 acc3[4][4];
#pragma unroll
  for (int r = 0; r < 4; ++r)
#pragma unroll
    for (int c = 0; c < 4; ++c) acc3[r][c] = (f32x4){0.f,0.f,0.f,0.f};
#pragma unroll
  for (int kc = 0; kc < 128; kc += 32) {
    bf16x8 afr[4];
#pragma unroll
    for (int r = 0; r < 4; ++r)
      afr[r] = *(const bf16x8*)(buf + (r*16 + lr)*136 + kc + lq*8);
#pragma unroll
    for (int c = 0; c < 4; ++c) {
      const bf16x8 bfr = *(const bf16x8*)(W23t + (size_t)(wave*64 + c*16 + lr)*128 + kc + lq*8);
#pragma unroll
      for (int r = 0; r < 4; ++r)
        acc3[r][c] = __builtin_amdgcn_mfma_f32_16x16x32_bf16(afr[r], bfr, acc3[r][c], 0, 0, 0);
    }
  }
  __syncthreads();   // all waves done reading hA -> safe to overwrite buf
  // epilogue: acc3v = (acc3 + c23[col]) * mk[row]; bf16 -> buf; stats on f32
#pragma unroll
  for (int c = 0; c < 4; ++c) {
    const int col = wave*64 + c*16 + lr;
    const float cc3 = c23[col];
    float sS = 0.f, sQ = 0.f;
#pragma unroll
    for (int r = 0; r < 4; ++r) {
      const int base = r*16 + lq*4;
#pragma unroll
      for (int i = 0; i < 4; i += 2) {
        const float a0 = (acc3[r][c][i]   + cc3) * mk[base + i];
        const float a1 = (acc3[r][c][i+1] + cc3) * mk[base + i + 1];
        const unsigned int u = cvt_pk_bf16(a0, a1);
        buf[(base + i    )*264 + col] = (u16)u;
        buf[(base + i + 1)*264 + col] = (u16)(u >> 16);
        sS += a0 + a1;
        sQ += a0*a0 + a1*a1;
      }
    }
    sS += __shfl_xor(sS, 16, 64);
    sS += __shfl_xor(sS, 32, 64);
    sQ += __shfl_xor(sQ, 16, 64);
    sQ += __shfl_xor(sQ, 32, 64);
    if (lq == 0) {
      s2sum[(size_t)rt*256 + col] = sS;
      s2sq [(size_t)rt*256 + col] = sQ;
    }
  }
  __syncthreads();
  // coalesced store acc3 tile -> global
  for (int it = tid; it < 64*32; it += 256) {
    const int row = it >> 5, c8 = it & 31;
    *(uint4*)(acc3buf + (size_t)(row0 + row)*256 + c8*8) = *(const uint4*)(buf + row*264 + c8*8);
  }
}

// ---------- FUSED pool/P/BN2: 512 blocks x 512 thr.
//   Block b: pool-reduce -> P[b] = pooled@W3b + b3 (K split over 2 thread-halves);
//   per-batch BN2 fold -> atomicAdd into midS/midQ (device-scope, 256 bins);
//   last-finishing block computes a2/sh2 (threadfence + counter pattern). ----------
__global__ __launch_bounds__(512) void k_pool2(
    const float* __restrict__ poolpart, const float* __restrict__ W3,
    const float* __restrict__ b3,
    const float* __restrict__ s2sum, const float* __restrict__ s2sq,
    const float* __restrict__ cntbf, const float* __restrict__ cntf,
    const float* __restrict__ g2, const float* __restrict__ be2,
    float* __restrict__ P, float* __restrict__ midS, float* __restrict__ midQ,
    float* __restrict__ a2, float* __restrict__ sh2, int* __restrict__ ctr) {
  __shared__ float pl[256];
  __shared__ float part2[2][256];
  __shared__ int lastdone;
  const int b = blockIdx.x, tid = threadIdx.x;
  if (tid < 256) {
    float m = poolpart[((size_t)b*8)*256 + tid];
#pragma unroll
    for (int s = 1; s < 8; ++s) m = fmaxf(m, poolpart[((size_t)(b*8+s))*256 + tid]);
    pl[tid] = m;
  }
  __syncthreads();
  // matvec: thread (col = tid&255, half = tid>>8) sums 128 of 256 K-terms
  {
    const int col = tid & 255, half = tid >> 8;
    const int cbase = half*128;
    float a0 = 0.f, a1 = 0.f, a2v = 0.f, a3 = 0.f;
    for (int c = cbase; c < cbase + 128; c += 4) {
      a0 = fmaf(pl[c  ], W3[(size_t)(256 + c    )*256 + col], a0);
      a1 = fmaf(pl[c+1], W3[(size_t)(256 + c + 1)*256 + col], a1);
      a2v= fmaf(pl[c+2], W3[(size_t)(256 + c + 2)*256 + col], a2v);
      a3 = fmaf(pl[c+3], W3[(size_t)(256 + c + 3)*256 + col], a3);
    }
    part2[half][col] = (a0 + a1) + (a2v + a3);
  }
  __syncthreads();
  if (tid < 256) {
    const float p = part2[0][tid] + part2[1][tid] + b3[tid];
    P[(size_t)b*256 + tid] = p;
    float S = 0.f, Q = 0.f;
#pragma unroll
    for (int s = 0; s < 8; ++s) {
      S += s2sum[(size_t)(b*8 + s)*256 + tid];
      Q += s2sq [(size_t)(b*8 + s)*256 + tid];
    }
    const float cntb = cntbf[b];
    atomicAdd(&midS[tid], fmaf(cntb, p, S));
    atomicAdd(&midQ[tid], fmaf(cntb, p*p, fmaf(2.f*p, S, Q)));
  }
  __threadfence();
  __syncthreads();
  if (tid == 0) lastdone = atomicAdd(ctr, 1);
  __syncthreads();
  if (lastdone == 511 && tid < 256) {
    // all 512 blocks' adds are visible (device-scope atomics + fences)
    const float s = atomicAdd(&midS[tid], 0.f);
    const float q = atomicAdd(&midQ[tid], 0.f);
    const float cf = *cntf;
    const float mean = s / cf;
    float var = q / cf - mean*mean; if (var < 0.f) var = 0.f;
    const float a = g2[tid] * rsqrtf(var + EPSV);
    a2[tid]  = a;
    sh2[tid] = be2[tid] - mean*a;
  }
}

// ---------- GEMM4 (proven R7/R10 streaming): one block per BATCH, seg-loop,
//            W4t in regs (kc8 loop FULLY unrolled - rule #20). ----------
__global__ __launch_bounds__(512, 4) void k_gemm4(
    const u16* __restrict__ acc3buf, const void* __restrict__ mask, const int* __restrict__ modep,
    const float* __restrict__ P, const float* __restrict__ a2, const float* __restrict__ sh2,
    const u16* __restrict__ W4t, const float* __restrict__ b4,
    float* __restrict__ out) {
  __shared__ u16 a2t[64*264];   // 33792 B  [row][k] pitch 264
  __shared__ float a2l[256], s2b[256];
  __shared__ float mk[64];
  const int mode = *modep;
  const int tid = threadIdx.x;
  const int b = blockIdx.x;      // batch
  const int wave = tid >> 6, lane = tid & 63;
  const int lr = lane & 15, lq = lane >> 4;
  const size_t rowbase = (size_t)b*512;
  if (tid < 256) {
    const float aa = a2[tid];
    a2l[tid] = aa;
    s2b[tid] = fmaf(P[(size_t)b*256 + tid], aa, sh2[tid]);
  }
  bf16x8 bw[8];
#pragma unroll
  for (int j = 0; j < 8; ++j)
    bw[j] = *(const bf16x8*)(W4t + (size_t)(wave*16 + lr)*256 + j*32 + lq*8);
  const float bb = b4[wave*16 + lr];
  float cm = -1e38f;
  uint4 u[4];
#pragma unroll
  for (int it = 0; it < 4; ++it) {
    const int j = tid + it*512;
    u[it] = *(const uint4*)(acc3buf + (rowbase + (j >> 5))*256 + (j & 31)*8);
  }
  for (int seg = 0; seg < 8; ++seg) {
    __syncthreads();
#pragma unroll
    for (int it = 0; it < 4; ++it) {
      const int j = tid + it*512;
      const int row = j >> 5, c8 = j & 31;
      const u16* us = (const u16*)&u[it];
      unsigned int pk[4];
#pragma unroll
      for (int jj = 0; jj < 4; ++jj) {
        const int cc0 = c8*8 + jj*2, cc1 = cc0 + 1;
        const float z0 = fmaf(bf2f(us[jj*2    ]), a2l[cc0], s2b[cc0]);
        const float z1 = fmaf(bf2f(us[jj*2 + 1]), a2l[cc1], s2b[cc1]);
        pk[jj] = cvt_pk_bf16(fmaxf(z0, 0.f), fmaxf(z1, 0.f));
      }
      *(uint4*)(a2t + row*264 + c8*8) = *(const uint4*)pk;
    }
    if (tid < 64) mk[tid] = read_mask(mask, (int)(rowbase + seg*64 + tid), mode);
    if (seg < 7) {
#pragma unroll
      for (int it = 0; it < 4; ++it) {
        const int j = tid + it*512;
        u[it] = *(const uint4*)(acc3buf + (rowbase + (seg + 1)*64 + (j >> 5))*256 + (j & 31)*8);
      }
    }
    __syncthreads();
    f32x4 acc[4];
#pragma unroll
    for (int r = 0; r < 4; ++r) acc[r] = (f32x4){0.f,0.f,0.f,0.f};
#pragma unroll
    for (int kc8 = 0; kc8 < 8; ++kc8) {
      bf16x8 afr[4];
#pragma unroll
      for (int r = 0; r < 4; ++r)
        afr[r] = *(const bf16x8*)(a2t + (r*16 + lr)*264 + kc8*32 + lq*8);
#pragma unroll
      for (int r = 0; r < 4; ++r)
        acc[r] = __builtin_amdgcn_mfma_f32_16x16x32_bf16(afr[r], bw[kc8], acc[r], 0, 0, 0);
    }
#pragma unroll
    for (int r = 0; r < 4; ++r) {
#pragma unroll
      for (int i = 0; i < 4; ++i)
        cm = fmaxf(cm, (acc[r][i] + bb) * mk[r*16 + lq*4 + i]);
    }
  }
  cm = fmaxf(cm, __shfl_xor(cm, 16, 64));
  cm = fmaxf(cm, __shfl_xor(cm, 32, 64));
  if (lq == 0) out[(size_t)b*128 + wave*16 + lr] = cm;
}

extern "C" void kernel_launch(void* const* d_in, const int* in_sizes, int n_in,
                              void* d_out, int out_size, void* d_ws, size_t ws_size,
                              hipStream_t stream) {
  const float* x    = (const float*)d_in[0];
  const void*  mask = d_in[1];
  const float* W1   = (const float*)d_in[2];
  const float* b1   = (const float*)d_in[3];
  const float* g1   = (const float*)d_in[4];
  const float* be1  = (const float*)d_in[5];
  const float* W2   = (const float*)d_in[6];
  const float* b2   = (const float*)d_in[7];
  const float* W3   = (const float*)d_in[8];
  const float* b3   = (const float*)d_in[9];
  const float* g2   = (const float*)d_in[10];
  const float* be2  = (const float*)d_in[11];
  const float* W4   = (const float*)d_in[12];
  const float* b4   = (const float*)d_in[13];
  float* out = (float*)d_out;

  char* ws = (char*)d_ws;
  size_t off = 0;
  auto take = [&](size_t bytes) -> char* {
    char* p = ws + off;
    off = (off + bytes + 255) & ~(size_t)255;
    return p;
  };
  u16*   acc3buf = (u16*)  take((size_t)MROWS*256*2);   // 128 MiB
  float* part    = (float*)take((size_t)128*32*4);
  float* cntbf   = (float*)take((size_t)512*4);
  float* w1p     = (float*)take(768*4);
  float* c1p     = (float*)take(128*4);
  float* cntf    = (float*)take(256);
  float* poolpart= (float*)take((size_t)512*8*256*4);
  float* P       = (float*)take((size_t)512*256*4);
  float* s2sum   = (float*)take((size_t)RT*256*4);
  float* s2sq    = (float*)take((size_t)RT*256*4);
  float* midS    = (float*)take((size_t)256*4);
  float* midQ    = (float*)take((size_t)256*4);
  float* a2      = (float*)take(256*4);
  float* sh2     = (float*)take(256*4);
  int*   modep   = (int*)  take(256);
  int*   ctr     = (int*)  take(256);
  u16*   w2t     = (u16*)  take((size_t)256*128*2);
  u16*   w23t    = (u16*)  take((size_t)256*128*2);
  u16*   w4t     = (u16*)  take((size_t)128*256*2);
  float* c23     = (float*)take(256*4);

  k_prep<<<386, 256, 0, stream>>>(W2, W3, W4, b2, (const unsigned char*)mask,
                                  w2t, w4t, w23t, c23, modep, midS, midQ, ctr);
  k_stats1<<<128, 256, 0, stream>>>(x, mask, modep, part, cntbf);
  k_fin1<<<1, 128, 0, stream>>>(part, W1, b1, g1, be1, w1p, c1p, cntf);
  k_mega<<<RT, 256, 0, stream>>>(x, mask, modep, w1p, c1p, w2t, b2, w23t, c23,
                                 acc3buf, poolpart, s2sum, s2sq);
  k_pool2<<<512, 512, 0, stream>>>(poolpart, W3, b3, s2sum, s2sq, cntbf, cntf,
                                   g2, be2, P, midS, midQ, a2, sh2, ctr);
  k_gemm4<<<512, 512, 0, stream>>>(acc3buf, mask, modep, P, a2, sh2, w4t, b4, out);
}

// Round 12
// 241.714 us; speedup vs baseline: 1.2552x; 1.2552x over previous
//
#include <hip/hip_runtime.h>
#include <stdint.h>

#define BB   512
#define NN   512
#define MROWS (BB*NN)      // 262144
#define RT   (MROWS/64)    // 4096 row tiles of 64
#define EPSV 1e-5f

typedef unsigned short u16;
typedef __attribute__((ext_vector_type(8))) short bf16x8;
typedef __attribute__((ext_vector_type(4))) float f32x4;

// ---------- helpers ----------
__device__ __forceinline__ float read_mask(const void* mp, int r, int mode) {
  if (mode == 0) return ((const unsigned char*)mp)[r] ? 1.f : 0.f;
  if (mode == 1) return ((const unsigned int*)mp)[r] ? 1.f : 0.f;
  return ((const unsigned long long*)mp)[r] ? 1.f : 0.f;
}

__device__ __forceinline__ u16 f2bf(float f) {
  union { float f; unsigned int u; } v; v.f = f;
  unsigned int u = v.u;
  return (u16)((u + 0x7FFFu + ((u >> 16) & 1u)) >> 16);
}

__device__ __forceinline__ float bf2f(u16 b) {
  union { unsigned int u; float f; } t;
  t.u = ((unsigned int)b) << 16;
  return t.f;
}

// packed f32x2 -> bf16x2 (RTNE, identical to f2bf), 1 VALU instr for 2 values
__device__ __forceinline__ unsigned int cvt_pk_bf16(float lo, float hi) {
  unsigned int r;
  asm("v_cvt_pk_bf16_f32 %0, %1, %2" : "=v"(r) : "v"(lo), "v"(hi));
  return r;
}

// ---------- merged weight prep + mask-mode detect ----------
// blocks 0..255: W2t/W4t; 256..384: W23t + c23; 385: detect.
__global__ __launch_bounds__(256) void k_prep(
    const float* __restrict__ W2, const float* __restrict__ W3, const float* __restrict__ W4,
    const float* __restrict__ b2, const unsigned char* __restrict__ mu,
    u16* __restrict__ w2t, u16* __restrict__ w4t,
    u16* __restrict__ w23t, float* __restrict__ c23, int* __restrict__ mode) {
  __shared__ float row[256];
  __shared__ int c1s, c4s;
  const int blk = blockIdx.x;
  if (blk < 256) {
    const int idx = blk*256 + threadIdx.x;  // < 65536
    if (idx < 32768) {                 // W2t [256 n][128 k]
      const int n = idx >> 7, k = idx & 127;
      w2t[idx] = f2bf(W2[(size_t)k*256 + n]);
    } else {                           // W4t [128 n][256 k]
      const int j = idx - 32768;
      const int n = j >> 8, k = j & 255;
      w4t[j] = f2bf(W4[(size_t)k*128 + n]);
    }
  } else if (blk < 385) {
    const int n = threadIdx.x;
    const int k = blk - 256;   // 0..128; k==128 computes c23
    if (k < 128) {
      row[n] = W2[(size_t)k*256 + n];
      __syncthreads();
      float a0 = 0.f, a1 = 0.f, a2v = 0.f, a3 = 0.f;
      for (int j = 0; j < 256; j += 4) {
        a0 = fmaf(row[j  ], W3[(size_t)(j    )*256 + n], a0);
        a1 = fmaf(row[j+1], W3[(size_t)(j + 1)*256 + n], a1);
        a2v= fmaf(row[j+2], W3[(size_t)(j + 2)*256 + n], a2v);
        a3 = fmaf(row[j+3], W3[(size_t)(j + 3)*256 + n], a3);
      }
      w23t[(size_t)n*128 + k] = f2bf(((a0 + a1) + (a2v + a3)));
    } else {
      float a0 = 0.f, a1 = 0.f, a2v = 0.f, a3 = 0.f;
      for (int j = 0; j < 256; j += 4) {
        a0 = fmaf(b2[j  ], W3[(size_t)(j    )*256 + n], a0);
        a1 = fmaf(b2[j+1], W3[(size_t)(j + 1)*256 + n], a1);
        a2v= fmaf(b2[j+2], W3[(size_t)(j + 2)*256 + n], a2v);
        a3 = fmaf(b2[j+3], W3[(size_t)(j + 3)*256 + n], a3);
      }
      c23[n] = ((a0 + a1) + (a2v + a3));
    }
  } else {
    if (threadIdx.x == 0) { c1s = 0; c4s = 0; }
    __syncthreads();
    for (int i = threadIdx.x; i < 4096; i += 256) {
      const unsigned char b = mu[i];
      if (b) {
        if ((i & 3) == 1) atomicAdd(&c1s, 1);
        if ((i & 7) == 4) atomicAdd(&c4s, 1);
      }
    }
    __syncthreads();
    if (threadIdx.x == 0) *mode = c1s ? 0 : (c4s ? 1 : 2);
  }
}

// ---------- kernel 1: CLOSED-FORM BN1 stats via x moments ----------
// part[blk][32]: 0..5 Sx, 6..26 Sxx (packed upper tri), 27 unused, 28..31 per-batch counts.
__global__ __launch_bounds__(256) void k_stats1(
    const float* __restrict__ x, const void* __restrict__ mask,
    const int* __restrict__ modep,
    float* __restrict__ part, float* __restrict__ cntbf) {
  const int mode = *modep;
  const int tid = threadIdx.x;
  const int blk = blockIdx.x;          // handles batches 4*blk .. 4*blk+3
  float sx[6] = {0,0,0,0,0,0};
  float sxx[21] = {0};
  float cntq[4] = {0,0,0,0};
#pragma unroll
  for (int it = 0; it < 8; ++it) {
    const int r = blk*2048 + it*256 + tid;
    const float mv = read_mask(mask, r, mode);
    const float* xr = x + (size_t)r*6;
    const float2 p0 = *(const float2*)(xr);
    const float2 p1 = *(const float2*)(xr + 2);
    const float2 p2 = *(const float2*)(xr + 4);
    float v[6] = {p0.x, p0.y, p1.x, p1.y, p2.x, p2.y};
    cntq[it >> 1] += mv;
    int idx = 0;
#pragma unroll
    for (int j = 0; j < 6; ++j) {
      sx[j] = fmaf(mv, v[j], sx[j]);
      const float mj = mv * v[j];
#pragma unroll
      for (int k = j; k < 6; ++k) { sxx[idx] = fmaf(mj, v[k], sxx[idx]); ++idx; }
    }
  }
  float vals[32];
#pragma unroll
  for (int j = 0; j < 6; ++j) vals[j] = sx[j];
#pragma unroll
  for (int j = 0; j < 21; ++j) vals[6 + j] = sxx[j];
  vals[27] = 0.f;
#pragma unroll
  for (int q = 0; q < 4; ++q) vals[28 + q] = cntq[q];
#pragma unroll
  for (int j = 0; j < 32; ++j) {
#pragma unroll
    for (int m = 1; m <= 32; m <<= 1)
      vals[j] += __shfl_xor(vals[j], m, 64);
  }
  __shared__ float red[4][32];
  const int wave = tid >> 6, lane = tid & 63;
  if (lane == 0) {
#pragma unroll
    for (int j = 0; j < 32; ++j) red[wave][j] = vals[j];
  }
  __syncthreads();
  if (tid < 32) {
    const float tot = red[0][tid] + red[1][tid] + red[2][tid] + red[3][tid];
    part[(size_t)blk*32 + tid] = tot;
    if (tid >= 28) cntbf[blk*4 + (tid - 28)] = tot;
  }
}

// ---------- kernel 2: reduce moments + closed-form BN1 -> folded W1p, c1p ----------
__global__ __launch_bounds__(128) void k_fin1(
    const float* __restrict__ part,
    const float* __restrict__ W1, const float* __restrict__ b1,
    const float* __restrict__ g1, const float* __restrict__ be1,
    float* __restrict__ w1p, float* __restrict__ c1p, float* __restrict__ cntf) {
  __shared__ float tot[32];
  const int t = threadIdx.x;
  if (t < 32) {
    float a0 = 0.f, a1 = 0.f, a2v = 0.f, a3 = 0.f;
    for (int i = 0; i < 128; i += 4) {
      a0 += part[(size_t)(i    )*32 + t];
      a1 += part[(size_t)(i + 1)*32 + t];
      a2v+= part[(size_t)(i + 2)*32 + t];
      a3 += part[(size_t)(i + 3)*32 + t];
    }
    tot[t] = (a0 + a1) + (a2v + a3);
  }
  __syncthreads();
  float cnt = tot[28] + tot[29] + tot[30] + tot[31];
  if (cnt < 1.f) cnt = 1.f;
  if (t == 0) *cntf = cnt;
  const int c = t;
  float w[6];
#pragma unroll
  for (int k = 0; k < 6; ++k) w[k] = W1[k*128 + c];
  float s1 = 0.f;
#pragma unroll
  for (int k = 0; k < 6; ++k) s1 = fmaf(w[k], tot[k], s1);
  s1 /= cnt;
  float q = 0.f;
  {
    int idx = 6;
#pragma unroll
    for (int j = 0; j < 6; ++j) {
      q = fmaf(w[j]*w[j], tot[idx], q); ++idx;
#pragma unroll
      for (int k = j + 1; k < 6; ++k) { q = fmaf(2.f*w[j]*w[k], tot[idx], q); ++idx; }
    }
  }
  float var = q / cnt - s1*s1; if (var < 0.f) var = 0.f;
  const float mean = b1[c] + s1;
  const float a = g1[c] * rsqrtf(var + EPSV);
  c1p[c] = fmaf(b1[c], a, be1[c] - mean*a);
#pragma unroll
  for (int k = 0; k < 6; ++k) w1p[k*128 + c] = W1[k*128 + c] * a;
}

// ---------- MEGA kernel (proven 101 us): GEMM1+BN1+ReLU -> hA;
//   GEMM2 (K=128) -> pool col-max only; GEMM23 (K=128) -> acc3 bf16 store + BN2 stats ----------
__global__ __launch_bounds__(256, 4) void k_mega(
    const float* __restrict__ x, const void* __restrict__ mask, const int* __restrict__ modep,
    const float* __restrict__ w1p, const float* __restrict__ c1p,
    const u16* __restrict__ W2t, const float* __restrict__ b2,
    const u16* __restrict__ W23t, const float* __restrict__ c23,
    u16* __restrict__ acc3buf, float* __restrict__ poolpart,
    float* __restrict__ s2sum, float* __restrict__ s2sq) {
  __shared__ u16 buf[64*264];    // hA (pitch 136), later acc3 staging (pitch 264)
  __shared__ float xs[384];
  __shared__ float mk[64];
  const int mode = *modep;
  const int tid = threadIdx.x;
  const int rt = blockIdx.x;
  const int row0 = rt*64;
  const int b = rt >> 3, seg = rt & 7;
  for (int i = tid; i < 384; i += 256) xs[i] = x[(size_t)row0*6 + i];
  if (tid < 64) mk[tid] = read_mask(mask, row0 + tid, mode);
  __syncthreads();
  // phase 1: h1n = relu(x@W1' + c1') bf16 into hA (pitch 136 inside buf).
  {
    const int c0 = (tid & 31) * 4;
    const int r0 = (tid >> 5) * 8;
    float4 wv[6];
#pragma unroll
    for (int k = 0; k < 6; ++k) wv[k] = *(const float4*)(w1p + k*128 + c0);
    const float4 cc = *(const float4*)(c1p + c0);
#pragma unroll
    for (int r = 0; r < 8; ++r) {
      const int row = r0 + r;
      float xv[6];
#pragma unroll
      for (int k = 0; k < 6; ++k) xv[k] = xs[row*6 + k];
      float v0 = cc.x, v1 = cc.y, v2 = cc.z, v3 = cc.w;
#pragma unroll
      for (int k = 0; k < 6; ++k) {
        v0 = fmaf(xv[k], wv[k].x, v0);
        v1 = fmaf(xv[k], wv[k].y, v1);
        v2 = fmaf(xv[k], wv[k].z, v2);
        v3 = fmaf(xv[k], wv[k].w, v3);
      }
      uint2 z;
      z.x = cvt_pk_bf16(fmaxf(v0, 0.f), fmaxf(v1, 0.f));
      z.y = cvt_pk_bf16(fmaxf(v2, 0.f), fmaxf(v3, 0.f));
      *(uint2*)(buf + row*136 + c0) = z;
    }
  }
  __syncthreads();
  const int wave = tid >> 6, lane = tid & 63;
  const int lr = lane & 15, lq = lane >> 4;
  // phase 2: GEMM2 (64 x 256, K=128) -> pool col-max only (no store)
  {
    f32x4 acc[4][4];
#pragma unroll
    for (int r = 0; r < 4; ++r)
#pragma unroll
      for (int c = 0; c < 4; ++c) acc[r][c] = (f32x4){0.f,0.f,0.f,0.f};
#pragma unroll
    for (int kc = 0; kc < 128; kc += 32) {
      bf16x8 afr[4];
#pragma unroll
      for (int r = 0; r < 4; ++r)
        afr[r] = *(const bf16x8*)(buf + (r*16 + lr)*136 + kc + lq*8);
#pragma unroll
      for (int c = 0; c < 4; ++c) {
        const bf16x8 bfr = *(const bf16x8*)(W2t + (size_t)(wave*64 + c*16 + lr)*128 + kc + lq*8);
#pragma unroll
        for (int r = 0; r < 4; ++r)
          acc[r][c] = __builtin_amdgcn_mfma_f32_16x16x32_bf16(afr[r], bfr, acc[r][c], 0, 0, 0);
      }
    }
#pragma unroll
    for (int c = 0; c < 4; ++c) {
      const int col = wave*64 + c*16 + lr;
      const float bb = b2[col];
      float cm = -1e38f;
#pragma unroll
      for (int r = 0; r < 4; ++r) {
        const int base = r*16 + lq*4;
#pragma unroll
        for (int i = 0; i < 4; ++i)
          cm = fmaxf(cm, (acc[r][c][i] + bb) * mk[base + i]);
      }
      cm = fmaxf(cm, __shfl_xor(cm, 16, 64));
      cm = fmaxf(cm, __shfl_xor(cm, 32, 64));
      if (lq == 0) poolpart[((size_t)(b*8 + seg))*256 + col] = cm;
    }
  }
  // phase 23: acc3 = relu1 @ W23 (64 x 256, K=128) from hA -- no barrier needed
  f32x4 acc3[4][4];
#pragma unroll
  for (int r = 0; r < 4; ++r)
#pragma unroll
    for (int c = 0; c < 4; ++c) acc3[r][c] = (f32x4){0.f,0.f,0.f,0.f};
#pragma unroll
  for (int kc = 0; kc < 128; kc += 32) {
    bf16x8 afr[4];
#pragma unroll
    for (int r = 0; r < 4; ++r)
      afr[r] = *(const bf16x8*)(buf + (r*16 + lr)*136 + kc + lq*8);
#pragma unroll
    for (int c = 0; c < 4; ++c) {
      const bf16x8 bfr = *(const bf16x8*)(W23t + (size_t)(wave*64 + c*16 + lr)*128 + kc + lq*8);
#pragma unroll
      for (int r = 0; r < 4; ++r)
        acc3[r][c] = __builtin_amdgcn_mfma_f32_16x16x32_bf16(afr[r], bfr, acc3[r][c], 0, 0, 0);
    }
  }
  __syncthreads();   // all waves done reading hA -> safe to overwrite buf
  // epilogue: acc3v = (acc3 + c23[col]) * mk[row]; bf16 -> buf; stats on f32
#pragma unroll
  for (int c = 0; c < 4; ++c) {
    const int col = wave*64 + c*16 + lr;
    const float cc3 = c23[col];
    float sS = 0.f, sQ = 0.f;
#pragma unroll
    for (int r = 0; r < 4; ++r) {
      const int base = r*16 + lq*4;
#pragma unroll
      for (int i = 0; i < 4; i += 2) {
        const float a0 = (acc3[r][c][i]   + cc3) * mk[base + i];
        const float a1 = (acc3[r][c][i+1] + cc3) * mk[base + i + 1];
        const unsigned int u = cvt_pk_bf16(a0, a1);
        buf[(base + i    )*264 + col] = (u16)u;
        buf[(base + i + 1)*264 + col] = (u16)(u >> 16);
        sS += a0 + a1;
        sQ += a0*a0 + a1*a1;
      }
    }
    sS += __shfl_xor(sS, 16, 64);
    sS += __shfl_xor(sS, 32, 64);
    sQ += __shfl_xor(sQ, 16, 64);
    sQ += __shfl_xor(sQ, 32, 64);
    if (lq == 0) {
      s2sum[(size_t)rt*256 + col] = sS;
      s2sq [(size_t)rt*256 + col] = sQ;
    }
  }
  __syncthreads();
  // coalesced store acc3 tile -> global
  for (int it = tid; it < 64*32; it += 256) {
    const int row = it >> 5, c8 = it & 31;
    *(uint4*)(acc3buf + (size_t)(row0 + row)*256 + c8*8) = *(const uint4*)(buf + row*264 + c8*8);
  }
}

// ---------- pool reduce + P[b,:] = pooled[b]@W3[256:512] + b3 (512 thr, K-split, NO atomics) ----------
__global__ __launch_bounds__(512) void k_poolP(
    const float* __restrict__ poolpart, const float* __restrict__ W3,
    const float* __restrict__ b3, float* __restrict__ P) {
  __shared__ float pl[256];
  __shared__ float part2[256];
  const int b = blockIdx.x, tid = threadIdx.x;
  if (tid < 256) {
    float m = poolpart[((size_t)b*8)*256 + tid];
#pragma unroll
    for (int s = 1; s < 8; ++s) m = fmaxf(m, poolpart[((size_t)(b*8+s))*256 + tid]);
    pl[tid] = m;
  }
  __syncthreads();
  const int col = tid & 255, half = tid >> 8;
  const int cbase = half*128;
  float a0 = 0.f, a1 = 0.f, a2v = 0.f, a3 = 0.f;
  for (int c = cbase; c < cbase + 128; c += 4) {
    a0 = fmaf(pl[c  ], W3[(size_t)(256 + c    )*256 + col], a0);
    a1 = fmaf(pl[c+1], W3[(size_t)(256 + c + 1)*256 + col], a1);
    a2v= fmaf(pl[c+2], W3[(size_t)(256 + c + 2)*256 + col], a2v);
    a3 = fmaf(pl[c+3], W3[(size_t)(256 + c + 3)*256 + col], a3);
  }
  const float sum = (a0 + a1) + (a2v + a3);
  if (half == 1) part2[col] = sum;
  __syncthreads();
  if (half == 0) P[(size_t)b*256 + col] = sum + part2[col] + b3[col];
}

// ---------- fold P into BN2 partials + reduce 512 batches -> 64 slabs ----------
__global__ __launch_bounds__(256) void k_red2(
    const float* __restrict__ s2sum, const float* __restrict__ s2sq,
    const float* __restrict__ cntbf, const float* __restrict__ P,
    float* __restrict__ midS, float* __restrict__ midQ) {
  const int slab = blockIdx.x;  // 0..63
  const int c = threadIdx.x;
  float accS = 0.f, accQ = 0.f;
  for (int b = slab*8; b < slab*8 + 8; ++b) {
    const float cntb = cntbf[b];
    float S = 0.f, Q = 0.f;
#pragma unroll
    for (int s = 0; s < 8; ++s) {
      S += s2sum[(size_t)(b*8 + s)*256 + c];
      Q += s2sq [(size_t)(b*8 + s)*256 + c];
    }
    const float p = P[(size_t)b*256 + c];
    accS += fmaf(cntb, p, S);
    accQ += fmaf(cntb, p*p, fmaf(2.f*p, S, Q));
  }
  midS[slab*256 + c] = accS;
  midQ[slab*256 + c] = accQ;
}

// ---------- finalize BN2 ----------
__global__ __launch_bounds__(256) void k_fin2(
    const float* __restrict__ midS, const float* __restrict__ midQ,
    const float* __restrict__ cntf,
    const float* __restrict__ g2, const float* __restrict__ be2,
    float* __restrict__ a2, float* __restrict__ sh2) {
  const int c = threadIdx.x;
  float s = 0.f, q = 0.f;
#pragma unroll 8
  for (int k = 0; k < 64; ++k) { s += midS[k*256 + c]; q += midQ[k*256 + c]; }
  const float cf = *cntf;
  const float mean = s / cf;
  float var = q / cf - mean*mean; if (var < 0.f) var = 0.f;
  const float a = g2[c] * rsqrtf(var + EPSV);
  a2[c]  = a;
  sh2[c] = be2[c] - mean*a;
}

// ---------- GEMM4 v4: grid 1024 = (batch, half); each block does 4 segs.
//            4 blocks/CU (vs 2) -> double the outstanding HBM streams.
//            W4t in regs (kc8 loop FULLY unrolled - rule #20). ----------
__global__ __launch_bounds__(512, 4) void k_gemm4(
    const u16* __restrict__ acc3buf, const void* __restrict__ mask, const int* __restrict__ modep,
    const float* __restrict__ P, const float* __restrict__ a2, const float* __restrict__ sh2,
    const u16* __restrict__ W4t, const float* __restrict__ b4,
    float* __restrict__ outpart) {
  __shared__ u16 a2t[64*264];   // 33792 B  [row][k] pitch 264
  __shared__ float a2l[256], s2b[256];
  __shared__ float mk[64];
  const int mode = *modep;
  const int tid = threadIdx.x;
  const int b = blockIdx.x >> 1;        // batch
  const int half = blockIdx.x & 1;      // seg group: 4*half .. 4*half+3
  const int wave = tid >> 6, lane = tid & 63;
  const int lr = lane & 15, lq = lane >> 4;
  const size_t rowbase = (size_t)b*512 + half*256;
  if (tid < 256) {
    const float aa = a2[tid];
    a2l[tid] = aa;
    s2b[tid] = fmaf(P[(size_t)b*256 + tid], aa, sh2[tid]);
  }
  bf16x8 bw[8];
#pragma unroll
  for (int j = 0; j < 8; ++j)
    bw[j] = *(const bf16x8*)(W4t + (size_t)(wave*16 + lr)*256 + j*32 + lq*8);
  const float bb = b4[wave*16 + lr];
  float cm = -1e38f;
  uint4 u[4];
#pragma unroll
  for (int it = 0; it < 4; ++it) {
    const int j = tid + it*512;
    u[it] = *(const uint4*)(acc3buf + (rowbase + (j >> 5))*256 + (j & 31)*8);
  }
  for (int seg = 0; seg < 4; ++seg) {
    __syncthreads();
#pragma unroll
    for (int it = 0; it < 4; ++it) {
      const int j = tid + it*512;
      const int row = j >> 5, c8 = j & 31;
      const u16* us = (const u16*)&u[it];
      unsigned int pk[4];
#pragma unroll
      for (int jj = 0; jj < 4; ++jj) {
        const int cc0 = c8*8 + jj*2, cc1 = cc0 + 1;
        const float z0 = fmaf(bf2f(us[jj*2    ]), a2l[cc0], s2b[cc0]);
        const float z1 = fmaf(bf2f(us[jj*2 + 1]), a2l[cc1], s2b[cc1]);
        pk[jj] = cvt_pk_bf16(fmaxf(z0, 0.f), fmaxf(z1, 0.f));
      }
      *(uint4*)(a2t + row*264 + c8*8) = *(const uint4*)pk;
    }
    if (tid < 64) mk[tid] = read_mask(mask, (int)(rowbase + seg*64 + tid), mode);
    if (seg < 3) {
#pragma unroll
      for (int it = 0; it < 4; ++it) {
        const int j = tid + it*512;
        u[it] = *(const uint4*)(acc3buf + (rowbase + (seg + 1)*64 + (j >> 5))*256 + (j & 31)*8);
      }
    }
    __syncthreads();
    f32x4 acc[4];
#pragma unroll
    for (int r = 0; r < 4; ++r) acc[r] = (f32x4){0.f,0.f,0.f,0.f};
#pragma unroll
    for (int kc8 = 0; kc8 < 8; ++kc8) {
      bf16x8 afr[4];
#pragma unroll
      for (int r = 0; r < 4; ++r)
        afr[r] = *(const bf16x8*)(a2t + (r*16 + lr)*264 + kc8*32 + lq*8);
#pragma unroll
      for (int r = 0; r < 4; ++r)
        acc[r] = __builtin_amdgcn_mfma_f32_16x16x32_bf16(afr[r], bw[kc8], acc[r], 0, 0, 0);
    }
#pragma unroll
    for (int r = 0; r < 4; ++r) {
#pragma unroll
      for (int i = 0; i < 4; ++i)
        cm = fmaxf(cm, (acc[r][i] + bb) * mk[r*16 + lq*4 + i]);
    }
  }
  cm = fmaxf(cm, __shfl_xor(cm, 16, 64));
  cm = fmaxf(cm, __shfl_xor(cm, 32, 64));
  if (lq == 0) outpart[(size_t)blockIdx.x*128 + wave*16 + lr] = cm;
}

// ---------- reduce 2 half maxima -> out[b,e] ----------
__global__ __launch_bounds__(256) void k_outred2(
    const float* __restrict__ outpart, float* __restrict__ out) {
  const int idx = blockIdx.x*256 + threadIdx.x;  // < 65536
  const int b = idx >> 7, e = idx & 127;
  out[idx] = fmaxf(outpart[(size_t)(b*2)*128 + e], outpart[(size_t)(b*2 + 1)*128 + e]);
}

extern "C" void kernel_launch(void* const* d_in, const int* in_sizes, int n_in,
                              void* d_out, int out_size, void* d_ws, size_t ws_size,
                              hipStream_t stream) {
  const float* x    = (const float*)d_in[0];
  const void*  mask = d_in[1];
  const float* W1   = (const float*)d_in[2];
  const float* b1   = (const float*)d_in[3];
  const float* g1   = (const float*)d_in[4];
  const float* be1  = (const float*)d_in[5];
  const float* W2   = (const float*)d_in[6];
  const float* b2   = (const float*)d_in[7];
  const float* W3   = (const float*)d_in[8];
  const float* b3   = (const float*)d_in[9];
  const float* g2   = (const float*)d_in[10];
  const float* be2  = (const float*)d_in[11];
  const float* W4   = (const float*)d_in[12];
  const float* b4   = (const float*)d_in[13];
  float* out = (float*)d_out;

  char* ws = (char*)d_ws;
  size_t off = 0;
  auto take = [&](size_t bytes) -> char* {
    char* p = ws + off;
    off = (off + bytes + 255) & ~(size_t)255;
    return p;
  };
  u16*   acc3buf = (u16*)  take((size_t)MROWS*256*2);   // 128 MiB
  float* part    = (float*)take((size_t)128*32*4);
  float* cntbf   = (float*)take((size_t)512*4);
  float* w1p     = (float*)take(768*4);
  float* c1p     = (float*)take(128*4);
  float* cntf    = (float*)take(256);
  float* poolpart= (float*)take((size_t)512*8*256*4);
  float* P       = (float*)take((size_t)512*256*4);
  float* s2sum   = (float*)take((size_t)RT*256*4);
  float* s2sq    = (float*)take((size_t)RT*256*4);
  float* midS    = (float*)take((size_t)64*256*4);
  float* midQ    = (float*)take((size_t)64*256*4);
  float* a2      = (float*)take(256*4);
  float* sh2     = (float*)take(256*4);
  float* outpart = (float*)take((size_t)1024*128*4);
  int*   modep   = (int*)  take(256);
  u16*   w2t     = (u16*)  take((size_t)256*128*2);
  u16*   w23t    = (u16*)  take((size_t)256*128*2);
  u16*   w4t     = (u16*)  take((size_t)128*256*2);
  float* c23     = (float*)take(256*4);

  k_prep<<<386, 256, 0, stream>>>(W2, W3, W4, b2, (const unsigned char*)mask,
                                  w2t, w4t, w23t, c23, modep);
  k_stats1<<<128, 256, 0, stream>>>(x, mask, modep, part, cntbf);
  k_fin1<<<1, 128, 0, stream>>>(part, W1, b1, g1, be1, w1p, c1p, cntf);
  k_mega<<<RT, 256, 0, stream>>>(x, mask, modep, w1p, c1p, w2t, b2, w23t, c23,
                                 acc3buf, poolpart, s2sum, s2sq);
  k_poolP<<<512, 512, 0, stream>>>(poolpart, W3, b3, P);
  k_red2<<<64, 256, 0, stream>>>(s2sum, s2sq, cntbf, P, midS, midQ);
  k_fin2<<<1, 256, 0, stream>>>(midS, midQ, cntf, g2, be2, a2, sh2);
  k_gemm4<<<1024, 512, 0, stream>>>(acc3buf, mask, modep, P, a2, sh2, w4t, b4, outpart);
  k_outred2<<<256, 256, 0, stream>>>(outpart, out);
}

// Round 13
// 238.819 us; speedup vs baseline: 1.2704x; 1.0121x over previous
//
#include <hip/hip_runtime.h>
#include <stdint.h>

#define BB   512
#define NN   512
#define MROWS (BB*NN)      // 262144
#define RT   (MROWS/64)    // 4096 row tiles of 64
#define EPSV 1e-5f

typedef unsigned short u16;
typedef __attribute__((ext_vector_type(8))) short bf16x8;
typedef __attribute__((ext_vector_type(4))) float f32x4;

// ---------- helpers ----------
__device__ __forceinline__ float read_mask(const void* mp, int r, int mode) {
  if (mode == 0) return ((const unsigned char*)mp)[r] ? 1.f : 0.f;
  if (mode == 1) return ((const unsigned int*)mp)[r] ? 1.f : 0.f;
  return ((const unsigned long long*)mp)[r] ? 1.f : 0.f;
}

__device__ __forceinline__ u16 f2bf(float f) {
  union { float f; unsigned int u; } v; v.f = f;
  unsigned int u = v.u;
  return (u16)((u + 0x7FFFu + ((u >> 16) & 1u)) >> 16);
}

__device__ __forceinline__ float bf2f(u16 b) {
  union { unsigned int u; float f; } t;
  t.u = ((unsigned int)b) << 16;
  return t.f;
}

// packed f32x2 -> bf16x2 (RTNE, identical to f2bf), 1 VALU instr for 2 values
__device__ __forceinline__ unsigned int cvt_pk_bf16(float lo, float hi) {
  unsigned int r;
  asm("v_cvt_pk_bf16_f32 %0, %1, %2" : "=v"(r) : "v"(lo), "v"(hi));
  return r;
}

// ---------- merged weight prep + mask-mode detect ----------
// blocks 0..255: W2t/W4t; 256..384: W23t + c23; 385: detect.
__global__ __launch_bounds__(256) void k_prep(
    const float* __restrict__ W2, const float* __restrict__ W3, const float* __restrict__ W4,
    const float* __restrict__ b2, const unsigned char* __restrict__ mu,
    u16* __restrict__ w2t, u16* __restrict__ w4t,
    u16* __restrict__ w23t, float* __restrict__ c23, int* __restrict__ mode) {
  __shared__ float row[256];
  __shared__ int c1s, c4s;
  const int blk = blockIdx.x;
  if (blk < 256) {
    const int idx = blk*256 + threadIdx.x;  // < 65536
    if (idx < 32768) {                 // W2t [256 n][128 k]
      const int n = idx >> 7, k = idx & 127;
      w2t[idx] = f2bf(W2[(size_t)k*256 + n]);
    } else {                           // W4t [128 n][256 k]
      const int j = idx - 32768;
      const int n = j >> 8, k = j & 255;
      w4t[j] = f2bf(W4[(size_t)k*128 + n]);
    }
  } else if (blk < 385) {
    const int n = threadIdx.x;
    const int k = blk - 256;   // 0..128; k==128 computes c23
    if (k < 128) {
      row[n] = W2[(size_t)k*256 + n];
      __syncthreads();
      float a0 = 0.f, a1 = 0.f, a2v = 0.f, a3 = 0.f;
      for (int j = 0; j < 256; j += 4) {
        a0 = fmaf(row[j  ], W3[(size_t)(j    )*256 + n], a0);
        a1 = fmaf(row[j+1], W3[(size_t)(j + 1)*256 + n], a1);
        a2v= fmaf(row[j+2], W3[(size_t)(j + 2)*256 + n], a2v);
        a3 = fmaf(row[j+3], W3[(size_t)(j + 3)*256 + n], a3);
      }
      w23t[(size_t)n*128 + k] = f2bf(((a0 + a1) + (a2v + a3)));
    } else {
      float a0 = 0.f, a1 = 0.f, a2v = 0.f, a3 = 0.f;
      for (int j = 0; j < 256; j += 4) {
        a0 = fmaf(b2[j  ], W3[(size_t)(j    )*256 + n], a0);
        a1 = fmaf(b2[j+1], W3[(size_t)(j + 1)*256 + n], a1);
        a2v= fmaf(b2[j+2], W3[(size_t)(j + 2)*256 + n], a2v);
        a3 = fmaf(b2[j+3], W3[(size_t)(j + 3)*256 + n], a3);
      }
      c23[n] = ((a0 + a1) + (a2v + a3));
    }
  } else {
    if (threadIdx.x == 0) { c1s = 0; c4s = 0; }
    __syncthreads();
    for (int i = threadIdx.x; i < 4096; i += 256) {
      const unsigned char b = mu[i];
      if (b) {
        if ((i & 3) == 1) atomicAdd(&c1s, 1);
        if ((i & 7) == 4) atomicAdd(&c4s, 1);
      }
    }
    __syncthreads();
    if (threadIdx.x == 0) *mode = c1s ? 0 : (c4s ? 1 : 2);
  }
}

// ---------- kernel 1: CLOSED-FORM BN1 stats via x moments ----------
// part[blk][32]: 0..5 Sx, 6..26 Sxx (packed upper tri), 27 unused, 28..31 per-batch counts.
__global__ __launch_bounds__(256) void k_stats1(
    const float* __restrict__ x, const void* __restrict__ mask,
    const int* __restrict__ modep,
    float* __restrict__ part, float* __restrict__ cntbf) {
  const int mode = *modep;
  const int tid = threadIdx.x;
  const int blk = blockIdx.x;          // handles batches 4*blk .. 4*blk+3
  float sx[6] = {0,0,0,0,0,0};
  float sxx[21] = {0};
  float cntq[4] = {0,0,0,0};
#pragma unroll
  for (int it = 0; it < 8; ++it) {
    const int r = blk*2048 + it*256 + tid;
    const float mv = read_mask(mask, r, mode);
    const float* xr = x + (size_t)r*6;
    const float2 p0 = *(const float2*)(xr);
    const float2 p1 = *(const float2*)(xr + 2);
    const float2 p2 = *(const float2*)(xr + 4);
    float v[6] = {p0.x, p0.y, p1.x, p1.y, p2.x, p2.y};
    cntq[it >> 1] += mv;
    int idx = 0;
#pragma unroll
    for (int j = 0; j < 6; ++j) {
      sx[j] = fmaf(mv, v[j], sx[j]);
      const float mj = mv * v[j];
#pragma unroll
      for (int k = j; k < 6; ++k) { sxx[idx] = fmaf(mj, v[k], sxx[idx]); ++idx; }
    }
  }
  float vals[32];
#pragma unroll
  for (int j = 0; j < 6; ++j) vals[j] = sx[j];
#pragma unroll
  for (int j = 0; j < 21; ++j) vals[6 + j] = sxx[j];
  vals[27] = 0.f;
#pragma unroll
  for (int q = 0; q < 4; ++q) vals[28 + q] = cntq[q];
#pragma unroll
  for (int j = 0; j < 32; ++j) {
#pragma unroll
    for (int m = 1; m <= 32; m <<= 1)
      vals[j] += __shfl_xor(vals[j], m, 64);
  }
  __shared__ float red[4][32];
  const int wave = tid >> 6, lane = tid & 63;
  if (lane == 0) {
#pragma unroll
    for (int j = 0; j < 32; ++j) red[wave][j] = vals[j];
  }
  __syncthreads();
  if (tid < 32) {
    const float tot = red[0][tid] + red[1][tid] + red[2][tid] + red[3][tid];
    part[(size_t)blk*32 + tid] = tot;
    if (tid >= 28) cntbf[blk*4 + (tid - 28)] = tot;
  }
}

// ---------- kernel 2: reduce moments + closed-form BN1 -> folded bf16 W1pb, c1p ----------
__global__ __launch_bounds__(128) void k_fin1(
    const float* __restrict__ part,
    const float* __restrict__ W1, const float* __restrict__ b1,
    const float* __restrict__ g1, const float* __restrict__ be1,
    u16* __restrict__ w1pb, float* __restrict__ c1p, float* __restrict__ cntf) {
  __shared__ float tot[32];
  const int t = threadIdx.x;
  if (t < 32) {
    float a0 = 0.f, a1 = 0.f, a2v = 0.f, a3 = 0.f;
    for (int i = 0; i < 128; i += 4) {
      a0 += part[(size_t)(i    )*32 + t];
      a1 += part[(size_t)(i + 1)*32 + t];
      a2v+= part[(size_t)(i + 2)*32 + t];
      a3 += part[(size_t)(i + 3)*32 + t];
    }
    tot[t] = (a0 + a1) + (a2v + a3);
  }
  __syncthreads();
  float cnt = tot[28] + tot[29] + tot[30] + tot[31];
  if (cnt < 1.f) cnt = 1.f;
  if (t == 0) *cntf = cnt;
  const int c = t;
  float w[6];
#pragma unroll
  for (int k = 0; k < 6; ++k) w[k] = W1[k*128 + c];
  float s1 = 0.f;
#pragma unroll
  for (int k = 0; k < 6; ++k) s1 = fmaf(w[k], tot[k], s1);
  s1 /= cnt;
  float q = 0.f;
  {
    int idx = 6;
#pragma unroll
    for (int j = 0; j < 6; ++j) {
      q = fmaf(w[j]*w[j], tot[idx], q); ++idx;
#pragma unroll
      for (int k = j + 1; k < 6; ++k) { q = fmaf(2.f*w[j]*w[k], tot[idx], q); ++idx; }
    }
  }
  float var = q / cnt - s1*s1; if (var < 0.f) var = 0.f;
  const float mean = b1[c] + s1;
  const float a = g1[c] * rsqrtf(var + EPSV);
  c1p[c] = fmaf(b1[c], a, be1[c] - mean*a);
  // w1pb [128 c][32 k] bf16, k>=6 zero (K padded to 32 for MFMA phase1)
  {
    uint4 z0;
    z0.x = cvt_pk_bf16(w[0]*a, w[1]*a);
    z0.y = cvt_pk_bf16(w[2]*a, w[3]*a);
    z0.z = cvt_pk_bf16(w[4]*a, w[5]*a);
    z0.w = 0u;
    uint4 zz = {0u, 0u, 0u, 0u};
    *(uint4*)(w1pb + (size_t)c*32     ) = z0;
    *(uint4*)(w1pb + (size_t)c*32 +  8) = zz;
    *(uint4*)(w1pb + (size_t)c*32 + 16) = zz;
    *(uint4*)(w1pb + (size_t)c*32 + 24) = zz;
  }
}

// ---------- MEGA kernel: phase1 = MFMA (x bf16, K=32 zero-padded) -> hA;
//   GEMM2 (K=128) -> pool col-max only; GEMM23 (K=128) -> acc3 bf16 store + BN2 stats ----------
__global__ __launch_bounds__(256, 4) void k_mega(
    const float* __restrict__ x, const void* __restrict__ mask, const int* __restrict__ modep,
    const u16* __restrict__ w1pb, const float* __restrict__ c1p,
    const u16* __restrict__ W2t, const float* __restrict__ b2,
    const u16* __restrict__ W23t, const float* __restrict__ c23,
    u16* __restrict__ acc3buf, float* __restrict__ poolpart,
    float* __restrict__ s2sum, float* __restrict__ s2sq) {
  __shared__ u16 buf[64*264];    // hA (pitch 136) in front; xb [64][40] lives in the tail
  __shared__ float mk[64];
  u16* xb = buf + 64*136;        // 2560 u16 needed; tail has 8192 u16 free
  const int mode = *modep;
  const int tid = threadIdx.x;
  const int rt = blockIdx.x;
  const int row0 = rt*64;
  const int b = rt >> 3, seg = rt & 7;
  // stage x rows as bf16 into K=32 zero-padded tile + mask
  if (tid < 64) {
    const float* xr = x + (size_t)(row0 + tid)*6;
    const float2 p0 = *(const float2*)(xr);
    const float2 p1 = *(const float2*)(xr + 2);
    const float2 p2 = *(const float2*)(xr + 4);
    uint4 z0;
    z0.x = cvt_pk_bf16(p0.x, p0.y);
    z0.y = cvt_pk_bf16(p1.x, p1.y);
    z0.z = cvt_pk_bf16(p2.x, p2.y);
    z0.w = 0u;
    uint4 zz = {0u, 0u, 0u, 0u};
    *(uint4*)(xb + tid*40     ) = z0;
    *(uint4*)(xb + tid*40 +  8) = zz;
    *(uint4*)(xb + tid*40 + 16) = zz;
    *(uint4*)(xb + tid*40 + 24) = zz;
    mk[tid] = read_mask(mask, row0 + tid, mode);
  }
  __syncthreads();
  const int wave = tid >> 6, lane = tid & 63;
  const int lr = lane & 15, lq = lane >> 4;
  // phase 1: h1 = x@W1p via MFMA (one K=32 step), TRANSPOSED output (R3-verified):
  // acc[r][c] elem i: row = r*16 + lr, col = wave*32 + c*16 + lq*4 + i
  {
    bf16x8 afr[4];
#pragma unroll
    for (int r = 0; r < 4; ++r)
      afr[r] = *(const bf16x8*)(xb + (r*16 + lr)*40 + lq*8);
    f32x4 acc[4][2];
#pragma unroll
    for (int r = 0; r < 4; ++r)
#pragma unroll
      for (int c = 0; c < 2; ++c) acc[r][c] = (f32x4){0.f,0.f,0.f,0.f};
#pragma unroll
    for (int c = 0; c < 2; ++c) {
      const bf16x8 bfr = *(const bf16x8*)(w1pb + (size_t)(wave*32 + c*16 + lr)*32 + lq*8);
#pragma unroll
      for (int r = 0; r < 4; ++r)
        acc[r][c] = __builtin_amdgcn_mfma_f32_16x16x32_bf16(bfr, afr[r], acc[r][c], 0, 0, 0);
    }
    // epilogue: + c1p, relu, bf16 -> hA via b64 writes
#pragma unroll
    for (int c = 0; c < 2; ++c) {
      const int colb = wave*32 + c*16 + lq*4;
      const float4 cc = *(const float4*)(c1p + colb);
#pragma unroll
      for (int r = 0; r < 4; ++r) {
        const int row = r*16 + lr;
        uint2 z;
        z.x = cvt_pk_bf16(fmaxf(acc[r][c][0] + cc.x, 0.f), fmaxf(acc[r][c][1] + cc.y, 0.f));
        z.y = cvt_pk_bf16(fmaxf(acc[r][c][2] + cc.z, 0.f), fmaxf(acc[r][c][3] + cc.w, 0.f));
        *(uint2*)(buf + row*136 + colb) = z;
      }
    }
  }
  __syncthreads();
  // phase 2: GEMM2 (64 x 256, K=128) -> pool col-max only (no store)
  {
    f32x4 acc[4][4];
#pragma unroll
    for (int r = 0; r < 4; ++r)
#pragma unroll
      for (int c = 0; c < 4; ++c) acc[r][c] = (f32x4){0.f,0.f,0.f,0.f};
#pragma unroll
    for (int kc = 0; kc < 128; kc += 32) {
      bf16x8 afr[4];
#pragma unroll
      for (int r = 0; r < 4; ++r)
        afr[r] = *(const bf16x8*)(buf + (r*16 + lr)*136 + kc + lq*8);
#pragma unroll
      for (int c = 0; c < 4; ++c) {
        const bf16x8 bfr = *(const bf16x8*)(W2t + (size_t)(wave*64 + c*16 + lr)*128 + kc + lq*8);
#pragma unroll
        for (int r = 0; r < 4; ++r)
          acc[r][c] = __builtin_amdgcn_mfma_f32_16x16x32_bf16(afr[r], bfr, acc[r][c], 0, 0, 0);
      }
    }
#pragma unroll
    for (int c = 0; c < 4; ++c) {
      const int col = wave*64 + c*16 + lr;
      const float bb = b2[col];
      float cm = -1e38f;
#pragma unroll
      for (int r = 0; r < 4; ++r) {
        const int base = r*16 + lq*4;
#pragma unroll
        for (int i = 0; i < 4; ++i)
          cm = fmaxf(cm, (acc[r][c][i] + bb) * mk[base + i]);
      }
      cm = fmaxf(cm, __shfl_xor(cm, 16, 64));
      cm = fmaxf(cm, __shfl_xor(cm, 32, 64));
      if (lq == 0) poolpart[((size_t)(b*8 + seg))*256 + col] = cm;
    }
  }
  // phase 23: acc3 = relu1 @ W23 (64 x 256, K=128) from hA -- no barrier needed
  f32x4 acc3[4][4];
#pragma unroll
  for (int r = 0; r < 4; ++r)
#pragma unroll
    for (int c = 0; c < 4; ++c) acc3[r][c] = (f32x4){0.f,0.f,0.f,0.f};
#pragma unroll
  for (int kc = 0; kc < 128; kc += 32) {
    bf16x8 afr[4];
#pragma unroll
    for (int r = 0; r < 4; ++r)
      afr[r] = *(const bf16x8*)(buf + (r*16 + lr)*136 + kc + lq*8);
#pragma unroll
    for (int c = 0; c < 4; ++c) {
      const bf16x8 bfr = *(const bf16x8*)(W23t + (size_t)(wave*64 + c*16 + lr)*128 + kc + lq*8);
#pragma unroll
      for (int r = 0; r < 4; ++r)
        acc3[r][c] = __builtin_amdgcn_mfma_f32_16x16x32_bf16(afr[r], bfr, acc3[r][c], 0, 0, 0);
    }
  }
  __syncthreads();   // all waves done reading hA -> safe to overwrite buf
  // epilogue: acc3v = (acc3 + c23[col]) * mk[row]; bf16 -> buf; stats on f32
#pragma unroll
  for (int c = 0; c < 4; ++c) {
    const int col = wave*64 + c*16 + lr;
    const float cc3 = c23[col];
    float sS = 0.f, sQ = 0.f;
#pragma unroll
    for (int r = 0; r < 4; ++r) {
      const int base = r*16 + lq*4;
#pragma unroll
      for (int i = 0; i < 4; i += 2) {
        const float a0 = (acc3[r][c][i]   + cc3) * mk[base + i];
        const float a1 = (acc3[r][c][i+1] + cc3) * mk[base + i + 1];
        const unsigned int u = cvt_pk_bf16(a0, a1);
        buf[(base + i    )*264 + col] = (u16)u;
        buf[(base + i + 1)*264 + col] = (u16)(u >> 16);
        sS += a0 + a1;
        sQ += a0*a0 + a1*a1;
      }
    }
    sS += __shfl_xor(sS, 16, 64);
    sS += __shfl_xor(sS, 32, 64);
    sQ += __shfl_xor(sQ, 16, 64);
    sQ += __shfl_xor(sQ, 32, 64);
    if (lq == 0) {
      s2sum[(size_t)rt*256 + col] = sS;
      s2sq [(size_t)rt*256 + col] = sQ;
    }
  }
  __syncthreads();
  // coalesced store acc3 tile -> global
  for (int it = tid; it < 64*32; it += 256) {
    const int row = it >> 5, c8 = it & 31;
    *(uint4*)(acc3buf + (size_t)(row0 + row)*256 + c8*8) = *(const uint4*)(buf + row*264 + c8*8);
  }
}

// ---------- pool reduce + P[b,:] = pooled[b]@W3[256:512] + b3 (512 thr, K-split, NO atomics) ----------
__global__ __launch_bounds__(512) void k_poolP(
    const float* __restrict__ poolpart, const float* __restrict__ W3,
    const float* __restrict__ b3, float* __restrict__ P) {
  __shared__ float pl[256];
  __shared__ float part2[256];
  const int b = blockIdx.x, tid = threadIdx.x;
  if (tid < 256) {
    float m = poolpart[((size_t)b*8)*256 + tid];
#pragma unroll
    for (int s = 1; s < 8; ++s) m = fmaxf(m, poolpart[((size_t)(b*8+s))*256 + tid]);
    pl[tid] = m;
  }
  __syncthreads();
  const int col = tid & 255, half = tid >> 8;
  const int cbase = half*128;
  float a0 = 0.f, a1 = 0.f, a2v = 0.f, a3 = 0.f;
  for (int c = cbase; c < cbase + 128; c += 4) {
    a0 = fmaf(pl[c  ], W3[(size_t)(256 + c    )*256 + col], a0);
    a1 = fmaf(pl[c+1], W3[(size_t)(256 + c + 1)*256 + col], a1);
    a2v= fmaf(pl[c+2], W3[(size_t)(256 + c + 2)*256 + col], a2v);
    a3 = fmaf(pl[c+3], W3[(size_t)(256 + c + 3)*256 + col], a3);
  }
  const float sum = (a0 + a1) + (a2v + a3);
  if (half == 1) part2[col] = sum;
  __syncthreads();
  if (half == 0) P[(size_t)b*256 + col] = sum + part2[col] + b3[col];
}

// ---------- fold P into BN2 partials + reduce 512 batches -> 64 slabs ----------
__global__ __launch_bounds__(256) void k_red2(
    const float* __restrict__ s2sum, const float* __restrict__ s2sq,
    const float* __restrict__ cntbf, const float* __restrict__ P,
    float* __restrict__ midS, float* __restrict__ midQ) {
  const int slab = blockIdx.x;  // 0..63
  const int c = threadIdx.x;
  float accS = 0.f, accQ = 0.f;
  for (int b = slab*8; b < slab*8 + 8; ++b) {
    const float cntb = cntbf[b];
    float S = 0.f, Q = 0.f;
#pragma unroll
    for (int s = 0; s < 8; ++s) {
      S += s2sum[(size_t)(b*8 + s)*256 + c];
      Q += s2sq [(size_t)(b*8 + s)*256 + c];
    }
    const float p = P[(size_t)b*256 + c];
    accS += fmaf(cntb, p, S);
    accQ += fmaf(cntb, p*p, fmaf(2.f*p, S, Q));
  }
  midS[slab*256 + c] = accS;
  midQ[slab*256 + c] = accQ;
}

// ---------- finalize BN2 ----------
__global__ __launch_bounds__(256) void k_fin2(
    const float* __restrict__ midS, const float* __restrict__ midQ,
    const float* __restrict__ cntf,
    const float* __restrict__ g2, const float* __restrict__ be2,
    float* __restrict__ a2, float* __restrict__ sh2) {
  const int c = threadIdx.x;
  float s = 0.f, q = 0.f;
#pragma unroll 8
  for (int k = 0; k < 64; ++k) { s += midS[k*256 + c]; q += midQ[k*256 + c]; }
  const float cf = *cntf;
  const float mean = s / cf;
  float var = q / cf - mean*mean; if (var < 0.f) var = 0.f;
  const float a = g2[c] * rsqrtf(var + EPSV);
  a2[c]  = a;
  sh2[c] = be2[c] - mean*a;
}

// ---------- GEMM4 (R12): grid 1024 = (batch, half); each block does 4 segs.
//            W4t in regs (kc8 loop FULLY unrolled - rule #20). ----------
__global__ __launch_bounds__(512, 4) void k_gemm4(
    const u16* __restrict__ acc3buf, const void* __restrict__ mask, const int* __restrict__ modep,
    const float* __restrict__ P, const float* __restrict__ a2, const float* __restrict__ sh2,
    const u16* __restrict__ W4t, const float* __restrict__ b4,
    float* __restrict__ outpart) {
  __shared__ u16 a2t[64*264];   // 33792 B  [row][k] pitch 264
  __shared__ float a2l[256], s2b[256];
  __shared__ float mk[64];
  const int mode = *modep;
  const int tid = threadIdx.x;
  const int b = blockIdx.x >> 1;        // batch
  const int half = blockIdx.x & 1;      // seg group: 4*half .. 4*half+3
  const int wave = tid >> 6, lane = tid & 63;
  const int lr = lane & 15, lq = lane >> 4;
  const size_t rowbase = (size_t)b*512 + half*256;
  if (tid < 256) {
    const float aa = a2[tid];
    a2l[tid] = aa;
    s2b[tid] = fmaf(P[(size_t)b*256 + tid], aa, sh2[tid]);
  }
  bf16x8 bw[8];
#pragma unroll
  for (int j = 0; j < 8; ++j)
    bw[j] = *(const bf16x8*)(W4t + (size_t)(wave*16 + lr)*256 + j*32 + lq*8);
  const float bb = b4[wave*16 + lr];
  float cm = -1e38f;
  uint4 u[4];
#pragma unroll
  for (int it = 0; it < 4; ++it) {
    const int j = tid + it*512;
    u[it] = *(const uint4*)(acc3buf + (rowbase + (j >> 5))*256 + (j & 31)*8);
  }
  for (int seg = 0; seg < 4; ++seg) {
    __syncthreads();
#pragma unroll
    for (int it = 0; it < 4; ++it) {
      const int j = tid + it*512;
      const int row = j >> 5, c8 = j & 31;
      const u16* us = (const u16*)&u[it];
      unsigned int pk[4];
#pragma unroll
      for (int jj = 0; jj < 4; ++jj) {
        const int cc0 = c8*8 + jj*2, cc1 = cc0 + 1;
        const float z0 = fmaf(bf2f(us[jj*2    ]), a2l[cc0], s2b[cc0]);
        const float z1 = fmaf(bf2f(us[jj*2 + 1]), a2l[cc1], s2b[cc1]);
        pk[jj] = cvt_pk_bf16(fmaxf(z0, 0.f), fmaxf(z1, 0.f));
      }
      *(uint4*)(a2t + row*264 + c8*8) = *(const uint4*)pk;
    }
    if (tid < 64) mk[tid] = read_mask(mask, (int)(rowbase + seg*64 + tid), mode);
    if (seg < 3) {
#pragma unroll
      for (int it = 0; it < 4; ++it) {
        const int j = tid + it*512;
        u[it] = *(const uint4*)(acc3buf + (rowbase + (seg + 1)*64 + (j >> 5))*256 + (j & 31)*8);
      }
    }
    __syncthreads();
    f32x4 acc[4];
#pragma unroll
    for (int r = 0; r < 4; ++r) acc[r] = (f32x4){0.f,0.f,0.f,0.f};
#pragma unroll
    for (int kc8 = 0; kc8 < 8; ++kc8) {
      bf16x8 afr[4];
#pragma unroll
      for (int r = 0; r < 4; ++r)
        afr[r] = *(const bf16x8*)(a2t + (r*16 + lr)*264 + kc8*32 + lq*8);
#pragma unroll
      for (int r = 0; r < 4; ++r)
        acc[r] = __builtin_amdgcn_mfma_f32_16x16x32_bf16(afr[r], bw[kc8], acc[r], 0, 0, 0);
    }
#pragma unroll
    for (int r = 0; r < 4; ++r) {
#pragma unroll
      for (int i = 0; i < 4; ++i)
        cm = fmaxf(cm, (acc[r][i] + bb) * mk[r*16 + lq*4 + i]);
    }
  }
  cm = fmaxf(cm, __shfl_xor(cm, 16, 64));
  cm = fmaxf(cm, __shfl_xor(cm, 32, 64));
  if (lq == 0) outpart[(size_t)blockIdx.x*128 + wave*16 + lr] = cm;
}

// ---------- reduce 2 half maxima -> out[b,e] ----------
__global__ __launch_bounds__(256) void k_outred2(
    const float* __restrict__ outpart, float* __restrict__ out) {
  const int idx = blockIdx.x*256 + threadIdx.x;  // < 65536
  const int b = idx >> 7, e = idx & 127;
  out[idx] = fmaxf(outpart[(size_t)(b*2)*128 + e], outpart[(size_t)(b*2 + 1)*128 + e]);
}

extern "C" void kernel_launch(void* const* d_in, const int* in_sizes, int n_in,
                              void* d_out, int out_size, void* d_ws, size_t ws_size,
                              hipStream_t stream) {
  const float* x    = (const float*)d_in[0];
  const void*  mask = d_in[1];
  const float* W1   = (const float*)d_in[2];
  const float* b1   = (const float*)d_in[3];
  const float* g1   = (const float*)d_in[4];
  const float* be1  = (const float*)d_in[5];
  const float* W2   = (const float*)d_in[6];
  const float* b2   = (const float*)d_in[7];
  const float* W3   = (const float*)d_in[8];
  const float* b3   = (const float*)d_in[9];
  const float* g2   = (const float*)d_in[10];
  const float* be2  = (const float*)d_in[11];
  const float* W4   = (const float*)d_in[12];
  const float* b4   = (const float*)d_in[13];
  float* out = (float*)d_out;

  char* ws = (char*)d_ws;
  size_t off = 0;
  auto take = [&](size_t bytes) -> char* {
    char* p = ws + off;
    off = (off + bytes + 255) & ~(size_t)255;
    return p;
  };
  u16*   acc3buf = (u16*)  take((size_t)MROWS*256*2);   // 128 MiB
  float* part    = (float*)take((size_t)128*32*4);
  float* cntbf   = (float*)take((size_t)512*4);
  u16*   w1pb    = (u16*)  take((size_t)128*32*2);
  float* c1p     = (float*)take(128*4);
  float* cntf    = (float*)take(256);
  float* poolpart= (float*)take((size_t)512*8*256*4);
  float* P       = (float*)take((size_t)512*256*4);
  float* s2sum   = (float*)take((size_t)RT*256*4);
  float* s2sq    = (float*)take((size_t)RT*256*4);
  float* midS    = (float*)take((size_t)64*256*4);
  float* midQ    = (float*)take((size_t)64*256*4);
  float* a2      = (float*)take(256*4);
  float* sh2     = (float*)take(256*4);
  float* outpart = (float*)take((size_t)1024*128*4);
  int*   modep   = (int*)  take(256);
  u16*   w2t     = (u16*)  take((size_t)256*128*2);
  u16*   w23t    = (u16*)  take((size_t)256*128*2);
  u16*   w4t     = (u16*)  take((size_t)128*256*2);
  float* c23     = (float*)take(256*4);

  k_prep<<<386, 256, 0, stream>>>(W2, W3, W4, b2, (const unsigned char*)mask,
                                  w2t, w4t, w23t, c23, modep);
  k_stats1<<<128, 256, 0, stream>>>(x, mask, modep, part, cntbf);
  k_fin1<<<1, 128, 0, stream>>>(part, W1, b1, g1, be1, w1pb, c1p, cntf);
  k_mega<<<RT, 256, 0, stream>>>(x, mask, modep, w1pb, c1p, w2t, b2, w23t, c23,
                                 acc3buf, poolpart, s2sum, s2sq);
  k_poolP<<<512, 512, 0, stream>>>(poolpart, W3, b3, P);
  k_red2<<<64, 256, 0, stream>>>(s2sum, s2sq, cntbf, P, midS, midQ);
  k_fin2<<<1, 256, 0, stream>>>(midS, midQ, cntf, g2, be2, a2, sh2);
  k_gemm4<<<1024, 512, 0, stream>>>(acc3buf, mask, modep, P, a2, sh2, w4t, b4, outpart);
  k_outred2<<<256, 256, 0, stream>>>(outpart, out);
}